// Round 2
// baseline (126.438 us; speedup 1.0000x reference)
//
#include <hip/hip_runtime.h>
#include <hip/hip_bf16.h>

#define NEG_HUGE -3.402823466e+38f
#define RMAX 14              // register staging: supports len <= 896
#define SEG_BLK 256          // 4 waves per block, 1 wave per segment
#define SCAN_T 1024

// ---------------------------------------------------------------------------
// Kernel 1: exclusive prefix sum of scope[] (S int32) -> offsets[] (S int32)
// 1024 threads: serial chunk sum -> wave shfl inclusive scan -> wave-sum scan
// by thread 0 (16 values) -> serial chunk write-out.
// ---------------------------------------------------------------------------
__global__ __launch_bounds__(SCAN_T)
void scan_kernel(const int* __restrict__ scope,
                 int* __restrict__ offsets, int S) {
    __shared__ int waveSums[16];
    int tid  = threadIdx.x;
    int lane = tid & 63, wv = tid >> 6;
    int chunk = (S + SCAN_T - 1) / SCAN_T;
    int begin = tid * chunk;
    int end   = begin + chunk; if (end > S) end = S;
    int s = 0;
    for (int i = begin; i < end; ++i) s += scope[i];
    // inclusive scan of per-thread sums within the wave
    int inc = s;
#pragma unroll
    for (int o = 1; o < 64; o <<= 1) {
        int v = __shfl_up(inc, o, 64);
        if (lane >= o) inc += v;
    }
    if (lane == 63) waveSums[wv] = inc;
    __syncthreads();
    if (tid == 0) {
        int run = 0;
#pragma unroll
        for (int w = 0; w < 16; ++w) { int v = waveSums[w]; waveSums[w] = run; run += v; }
    }
    __syncthreads();
    int base = waveSums[wv] + (inc - s);   // exclusive prefix for this thread
    for (int i = begin; i < end; ++i) { offsets[i] = base; base += scope[i]; }
}

// ---------------------------------------------------------------------------
// Kernel 2: ONE WAVE per segment, 4 waves (256 threads) per block.
// Register staging (<= RMAX*64 elements), shfl_xor reductions, zero LDS,
// zero barriers. Streaming global fallback for oversized segments.
// ---------------------------------------------------------------------------
__global__ __launch_bounds__(SEG_BLK)
void seg_loss_wave(const float* __restrict__ means,
                   const float* __restrict__ targets,
                   const int* __restrict__ offsets,
                   const int* __restrict__ scope,
                   float* __restrict__ seg_out, int S) {
    int seg = blockIdx.x * (SEG_BLK >> 6) + (threadIdx.x >> 6);
    if (seg >= S) return;
    int lane  = threadIdx.x & 63;
    int start = offsets[seg];
    int len   = scope[seg];
    if (len <= 0) { if (lane == 0) seg_out[seg] = 0.f; return; }

    float tden = 0.f, mden = 0.f, A = 0.f, tmax, mmax;

    if (len <= RMAX * 64) {
        // ---- register-staged path (the common case) ----
        float tv[RMAX], mv[RMAX];
        tmax = NEG_HUGE; mmax = NEG_HUGE;
#pragma unroll
        for (int r = 0; r < RMAX; ++r) {
            int i = r * 64 + lane;
            bool ok = i < len;
            tv[r] = ok ? targets[start + i] : NEG_HUGE;
            mv[r] = ok ? means[start + i]   : NEG_HUGE;
            tmax = fmaxf(tmax, tv[r]);
            mmax = fmaxf(mmax, mv[r]);
        }
#pragma unroll
        for (int o = 32; o > 0; o >>= 1) {
            tmax = fmaxf(tmax, __shfl_xor(tmax, o, 64));
            mmax = fmaxf(mmax, __shfl_xor(mmax, o, 64));
        }
#pragma unroll
        for (int r = 0; r < RMAX; ++r) {
            int i = r * 64 + lane;
            if (i < len) {
                float et = __expf(tv[r] - tmax);
                float dm = mv[r] - mmax;
                tden += et;
                mden += __expf(dm);
                A    += et * dm;
            }
        }
    } else {
        // ---- streaming fallback (rare oversized segment) ----
        tmax = NEG_HUGE; mmax = NEG_HUGE;
        for (int i = lane; i < len; i += 64) {
            tmax = fmaxf(tmax, targets[start + i]);
            mmax = fmaxf(mmax, means[start + i]);
        }
#pragma unroll
        for (int o = 32; o > 0; o >>= 1) {
            tmax = fmaxf(tmax, __shfl_xor(tmax, o, 64));
            mmax = fmaxf(mmax, __shfl_xor(mmax, o, 64));
        }
        for (int i = lane; i < len; i += 64) {
            float et = __expf(targets[start + i] - tmax);
            float dm = means[start + i] - mmax;
            tden += et;
            mden += __expf(dm);
            A    += et * dm;
        }
    }

#pragma unroll
    for (int o = 32; o > 0; o >>= 1) {
        tden += __shfl_xor(tden, o, 64);
        mden += __shfl_xor(mden, o, 64);
        A    += __shfl_xor(A,    o, 64);
    }
    if (lane == 0) {
        // -sum(p*logq) = log(mden) - A/tden
        seg_out[seg] = logf(mden) - A / tden;
    }
}

// ---------------------------------------------------------------------------
// Kernel 3: deterministic sum of S per-segment losses, divide by S.
// ---------------------------------------------------------------------------
__global__ __launch_bounds__(1024)
void reduce_kernel(const float* __restrict__ seg_loss,
                   float* __restrict__ out, int S) {
    __shared__ float wsum[16];
    int tid = threadIdx.x;
    float s = 0.f;
    for (int i = tid; i < S; i += 1024) s += seg_loss[i];
#pragma unroll
    for (int o = 32; o > 0; o >>= 1) s += __shfl_down(s, o, 64);
    int lane = tid & 63, wave = tid >> 6;
    if (lane == 0) wsum[wave] = s;
    __syncthreads();
    if (tid == 0) {
        float tot = 0.f;
#pragma unroll
        for (int w = 0; w < 16; ++w) tot += wsum[w];
        out[0] = tot / (float)S;
    }
}

extern "C" void kernel_launch(void* const* d_in, const int* in_sizes, int n_in,
                              void* d_out, int out_size, void* d_ws, size_t ws_size,
                              hipStream_t stream) {
    const float* means   = (const float*)d_in[0];
    const int*   scope   = (const int*)d_in[1];
    const float* targets = (const float*)d_in[2];
    int S = in_sizes[1];
    float* out = (float*)d_out;

    int*   offsets = (int*)d_ws;
    float* segl    = (float*)((char*)d_ws + (size_t)S * sizeof(int));

    scan_kernel<<<1, SCAN_T, 0, stream>>>(scope, offsets, S);
    int segBlocks = (S + (SEG_BLK >> 6) - 1) / (SEG_BLK >> 6);
    seg_loss_wave<<<segBlocks, SEG_BLK, 0, stream>>>(means, targets, offsets, scope, segl, S);
    reduce_kernel<<<1, 1024, 0, stream>>>(segl, out, S);
}